// Round 1
// 96.168 us; speedup vs baseline: 1.2359x; 1.2359x over previous
//
#include <hip/hip_runtime.h>

#define B 8
#define N 8192
#define M 2048
#define NITER 4
#define BASE_ALPHA 0.1f
#define MARGIN 0.02f           // covers fp slack (~1e-4) on the NN-invariance bound

#define NTHR 1024              // 16 waves
#define NPT 32                 // point-lanes per split
#define NSPLIT 32              // j-splits per block
#define JS (M / NSPLIT)        // 64 y's per split
#define JQ (JS / 4)            // 16 j-quads per split
#define PT 8                   // points per thread
#define PPB (NPT * PT)         // 256 points per block
#define NBLK (B * N / PPB)     // 256 blocks
#define BPB (NBLK / B)         // 32 blocks per batch

// ws layout: pos4 float4[B*N] @0; aux uint2[B*N] @1MB (bits(md), LOGICAL nearest
// idx); slot0/slot1 float[B][BPB] double-buffered (kills the cross-block
// read-then-write race of a single slots array); mask uint[B*N] @OFF_MASK:
// bit s set iff split-s iter-0 min dist <= d0 + MARGIN. NN-invariance: the
// argmin cannot leave this set at iters 1-3 (see header theory).
#define OFF_AUX   (1024 * 1024)
#define OFF_SLOT0 (1536 * 1024)
#define OFF_SLOT1 (1540 * 1024)
#define OFF_MASK  (1544 * 1024)

typedef float f2 __attribute__((ext_vector_type(2)));

__device__ __forceinline__ unsigned int ord32(float t) {
    unsigned int u = __float_as_uint(t);
    return u ^ ((unsigned int)((int)u >> 31) | 0x80000000u);   // float order -> uint order
}
__device__ __forceinline__ float dec32(unsigned int h) {
    return __uint_as_float((h & 0x80000000u) ? (h ^ 0x80000000u) : ~h);
}

// ---------------- iter 0: full scan + split-mask emission ----------------
__global__ __launch_bounds__(NTHR, 4) void iter_kernel(const float* __restrict__ pred,
                                                       const float* __restrict__ partial,
                                                       float4* __restrict__ pos4,
                                                       uint2* __restrict__ aux,
                                                       float* __restrict__ slots,
                                                       unsigned int* __restrict__ maskbuf) {
    __shared__ float4 sX[M / 4], sY[M / 4], sZ[M / 4], sW[M / 4];  // 32 KB
    __shared__ float smint[NSPLIT][PPB];                           // 32 KB per-(split,point) min t
    __shared__ float4 lpos[PPB];
    __shared__ float redbuf[4];

    const int tid = threadIdx.x;
    const int b = blockIdx.x >> 5;
    const int blk = blockIdx.x & 31;
    const int gp0 = b * N + blk * PPB;

    // Build SoA tile. (-2y)*x bit-equal to reference's (-2x)*y.
    const float* pa = partial + b * M * 3;
    if (tid < M / 4) {
        int sp = tid & 31, jq = tid >> 5;
        const float* p0 = pa + (sp * JS + jq * 4) * 3;
        float a0 = p0[0], a1 = p0[1],  a2 = p0[2];
        float b0 = p0[3], b1 = p0[4],  b2 = p0[5];
        float c0 = p0[6], c1 = p0[7],  c2 = p0[8];
        float d0 = p0[9], d1 = p0[10], d2 = p0[11];
        sX[tid] = make_float4(-2.f * a0, -2.f * b0, -2.f * c0, -2.f * d0);
        sY[tid] = make_float4(-2.f * a1, -2.f * b1, -2.f * c1, -2.f * d1);
        sZ[tid] = make_float4(-2.f * a2, -2.f * b2, -2.f * c2, -2.f * d2);
        sW[tid] = make_float4(a0 * a0 + a1 * a1 + a2 * a2, b0 * b0 + b1 * b1 + b2 * b2,
                              c0 * c0 + c1 * c1 + c2 * c2, d0 * d0 + d1 * d1 + d2 * d2);
    }

    // Owners: refined_0 = pred (no update at iter 0).
    if (tid < PPB) {
        const int p = gp0 + tid;
        const float* pp = pred + (unsigned long long)p * 3;
        float rx = pp[0], ry = pp[1], rz = pp[2];
        float w = rx * rx + ry * ry + rz * rz;
        lpos[tid] = make_float4(rx, ry, rz, w);
        pos4[p] = make_float4(rx, ry, rz, w);
    }
    __syncthreads();

    const int split = tid >> 5;                    // 0..31 (uniform per half-wave)
    const int pt = tid & 31;

    // ---- pass 1: packed-f32 per-split min (2.0 VALU-instr/pair) ----
    f2 sx[PT], sy[PT], sz[PT];
    #pragma unroll
    for (int k = 0; k < PT; ++k) {
        float4 r = lpos[pt + k * NPT];
        sx[k] = (f2){r.x, r.x}; sy[k] = (f2){r.y, r.y}; sz[k] = (f2){r.z, r.z};
    }
    f2 acc[PT];
    #pragma unroll
    for (int k = 0; k < PT; ++k) acc[k] = (f2){3.402823466e+38f, 3.402823466e+38f};

    #pragma unroll 2
    for (int jq = 0; jq < JQ; ++jq) {
        float4 qx = sX[jq * 32 + split], qy = sY[jq * 32 + split];
        float4 qz = sZ[jq * 32 + split], qw = sW[jq * 32 + split];
        f2 qx01 = (f2){qx.x, qx.y}, qx23 = (f2){qx.z, qx.w};
        f2 qy01 = (f2){qy.x, qy.y}, qy23 = (f2){qy.z, qy.w};
        f2 qz01 = (f2){qz.x, qz.y}, qz23 = (f2){qz.z, qz.w};
        f2 qw01 = (f2){qw.x, qw.y}, qw23 = (f2){qw.z, qw.w};
        #pragma unroll
        for (int k = 0; k < PT; ++k) {
            f2 t01 = __builtin_elementwise_fma(sx[k], qx01,
                     __builtin_elementwise_fma(sy[k], qy01,
                     __builtin_elementwise_fma(sz[k], qz01, qw01)));
            f2 t23 = __builtin_elementwise_fma(sx[k], qx23,
                     __builtin_elementwise_fma(sy[k], qy23,
                     __builtin_elementwise_fma(sz[k], qz23, qw23)));
            acc[k] = __builtin_elementwise_min(acc[k],
                     __builtin_elementwise_min(t01, t23));     // exact, order-invariant
        }
    }

    // Deposit per-(point,split) minima; replaces the u64 shfl/lkeys merge.
    #pragma unroll
    for (int k = 0; k < PT; ++k)
        smint[split][pt + k * NPT] = fminf(acc[k].x, acc[k].y);
    __syncthreads();

    // ---- owners: lexmin over 32 splits, pass-2 exact first-argmin, mask ----
    if (tid < PPB) {
        float tstar = 3.402823466e+38f; int bsplit = 0;
        #pragma unroll
        for (int s = 0; s < NSPLIT; ++s) {
            float v = smint[s][tid];
            if (v < tstar) { tstar = v; bsplit = s; }          // tie -> smaller split
        }
        const float4 f4 = lpos[tid];
        const float md = sqrtf(fmaxf(f4.w + tstar, 0.0f));

        // pass 2: scalar fmaf chain bit-identical to pk halves; earliest j wins.
        float bt = 3.402823466e+38f; int bj = 0;
        for (int jq = 0; jq < JQ; ++jq) {
            float4 qx = sX[jq * 32 + bsplit], qy = sY[jq * 32 + bsplit];
            float4 qz = sZ[jq * 32 + bsplit], qw = sW[jq * 32 + bsplit];
            float t0 = fmaf(f4.x, qx.x, fmaf(f4.y, qy.x, fmaf(f4.z, qz.x, qw.x)));
            float t1 = fmaf(f4.x, qx.y, fmaf(f4.y, qy.y, fmaf(f4.z, qz.y, qw.y)));
            float t2 = fmaf(f4.x, qx.z, fmaf(f4.y, qy.z, fmaf(f4.z, qz.z, qw.z)));
            float t3 = fmaf(f4.x, qx.w, fmaf(f4.y, qy.w, fmaf(f4.z, qz.w, qw.w)));
            if (t0 < bt) { bt = t0; bj = jq * 4 + 0; }
            if (t1 < bt) { bt = t1; bj = jq * 4 + 1; }
            if (t2 < bt) { bt = t2; bj = jq * 4 + 2; }
            if (t3 < bt) { bt = t3; bj = jq * 4 + 3; }
        }
        aux[gp0 + tid] = make_uint2(__float_as_uint(md),
                                    (unsigned int)(bsplit * JS + bj));   // logical idx

        // Split mask: md_s <= md + MARGIN  <=>  t_s <= (md+MARGIN)^2 - w.
        // Always contains bsplit; conservative (inclusive) threshold.
        float mdm = md + MARGIN;
        float thr = fmaf(mdm, mdm, -f4.w);
        unsigned int mk = 0u;
        #pragma unroll
        for (int s = 0; s < NSPLIT; ++s)
            if (smint[s][tid] <= thr) mk |= (1u << s);
        maskbuf[gp0 + tid] = mk;

        float wm = md;
        #pragma unroll
        for (int o = 32; o > 0; o >>= 1) wm = fmaxf(wm, __shfl_down(wm, o));
        if ((tid & 63) == 0) redbuf[tid >> 6] = wm;
    }
    __syncthreads();
    if (tid == 0)
        slots[b * BPB + blk] = fmaxf(fmaxf(redbuf[0], redbuf[1]),
                                     fmaxf(redbuf[2], redbuf[3]));
}

// ---------------- iters 1..3: update + masked-split rescan only ----------------
// 4 threads/point (h = tid>>8 scans jq in [4h, 4h+4)); merge via (ord32(t), j)
// u64 lexmin == first-argmin. All arithmetic chains verbatim from iter_kernel.
__global__ __launch_bounds__(NTHR, 4) void light_kernel(const float* __restrict__ partial,
                                                        float4* __restrict__ pos4,
                                                        uint2* __restrict__ aux,
                                                        const unsigned int* __restrict__ maskbuf,
                                                        const float* __restrict__ slots_in,
                                                        float* __restrict__ slots_out) {
    __shared__ float4 sX[M / 4], sY[M / 4], sZ[M / 4], sW[M / 4];  // 32 KB
    __shared__ unsigned long long ukeys[3][PPB];                   // h=1..3 partials, 6 KB
    __shared__ float redbuf[4];
    __shared__ float mxsh;

    const int tid = threadIdx.x;
    const int b = blockIdx.x >> 5;
    const int blk = blockIdx.x & 31;
    const int gp0 = b * N + blk * PPB;

    const int pt = tid & (PPB - 1);
    const int h = tid >> 8;
    const int p = gp0 + pt;

    // Issue point-state loads BEFORE the barrier: the vmcnt(0) at __syncthreads
    // orders them ahead of h0's later pos4 store (no intra-block race).
    float4 f = pos4[p];
    uint2 a = aux[p];
    unsigned int mk = maskbuf[p];

    // Build SoA tile (verbatim).
    const float* pa = partial + b * M * 3;
    if (tid < M / 4) {
        int sp = tid & 31, jq = tid >> 5;
        const float* p0 = pa + (sp * JS + jq * 4) * 3;
        float a0 = p0[0], a1 = p0[1],  a2 = p0[2];
        float b0 = p0[3], b1 = p0[4],  b2 = p0[5];
        float c0 = p0[6], c1 = p0[7],  c2 = p0[8];
        float d0 = p0[9], d1 = p0[10], d2 = p0[11];
        sX[tid] = make_float4(-2.f * a0, -2.f * b0, -2.f * c0, -2.f * d0);
        sY[tid] = make_float4(-2.f * a1, -2.f * b1, -2.f * c1, -2.f * d1);
        sZ[tid] = make_float4(-2.f * a2, -2.f * b2, -2.f * c2, -2.f * d2);
        sW[tid] = make_float4(a0 * a0 + a1 * a1 + a2 * a2, b0 * b0 + b1 * b1 + b2 * b2,
                              c0 * c0 + c1 * c1 + c2 * c2, d0 * d0 + d1 * d1 + d2 * d2);
    }
    // Batch max of previous iteration (verbatim).
    if (tid < 64) {
        float v = slots_in[b * BPB + (tid & 31)];
        #pragma unroll
        for (int o = 16; o > 0; o >>= 1) v = fmaxf(v, __shfl_xor(v, o));
        if (tid == 0) mxsh = v;
    }
    __syncthreads();

    // Owner update (verbatim chains), computed redundantly by all 4 h-threads.
    float md0 = __uint_as_float(a.x);
    int lg = (int)a.y;                             // logical nearest idx
    int bs = lg >> 6, bjd = lg & 63;
    int i4 = ((bjd >> 2) * 32 + bs) * 4 + (bjd & 3);
    float ny0 = -0.5f * ((const float*)sX)[i4];    // exact y bits
    float ny1 = -0.5f * ((const float*)sY)[i4];
    float ny2 = -0.5f * ((const float*)sZ)[i4];
    float inv = 1.0f / (mxsh + 1e-6f);
    float alpha = BASE_ALPHA * (2.0f - md0 * inv);
    float rx = fmaf(alpha, ny0 - f.x, f.x);
    float ry = fmaf(alpha, ny1 - f.y, f.y);
    float rz = fmaf(alpha, ny2 - f.z, f.z);
    float w = rx * rx + ry * ry + rz * rz;
    if (h == 0) pos4[p] = make_float4(rx, ry, rz, w);

    // Masked rescan: ascending (s, jq, c) within thread -> first-argmin kept by
    // strict <; cross-h merge by (ord32(t), j) lexmin.
    float bt = 3.402823466e+38f; int bj = 0;
    unsigned int m = mk;
    while (m) {
        int s = __builtin_ctz(m); m &= m - 1;
        #pragma unroll
        for (int q = 0; q < 4; ++q) {
            int jq = h * 4 + q;
            float4 qx = sX[jq * 32 + s], qy = sY[jq * 32 + s];
            float4 qz = sZ[jq * 32 + s], qw = sW[jq * 32 + s];
            float t0 = fmaf(rx, qx.x, fmaf(ry, qy.x, fmaf(rz, qz.x, qw.x)));
            float t1 = fmaf(rx, qx.y, fmaf(ry, qy.y, fmaf(rz, qz.y, qw.y)));
            float t2 = fmaf(rx, qx.z, fmaf(ry, qy.z, fmaf(rz, qz.z, qw.z)));
            float t3 = fmaf(rx, qx.w, fmaf(ry, qy.w, fmaf(rz, qz.w, qw.w)));
            int j0 = s * JS + jq * 4;
            if (t0 < bt) { bt = t0; bj = j0 + 0; }
            if (t1 < bt) { bt = t1; bj = j0 + 1; }
            if (t2 < bt) { bt = t2; bj = j0 + 2; }
            if (t3 < bt) { bt = t3; bj = j0 + 3; }
        }
    }
    unsigned long long key = (((unsigned long long)ord32(bt)) << 32) | (unsigned int)bj;
    if (h) ukeys[h - 1][pt] = key;
    __syncthreads();

    if (h == 0) {
        #pragma unroll
        for (int r = 0; r < 3; ++r) {
            unsigned long long c = ukeys[r][pt];
            if (c < key) key = c;
        }
        float tstar = dec32((unsigned int)(key >> 32));
        float mdn = sqrtf(fmaxf(w + tstar, 0.0f));
        aux[p] = make_uint2(__float_as_uint(mdn), (unsigned int)(key & 0xFFFFFFFFu));
        float wm = mdn;
        #pragma unroll
        for (int o = 32; o > 0; o >>= 1) wm = fmaxf(wm, __shfl_down(wm, o));
        if ((tid & 63) == 0) redbuf[tid >> 6] = wm;
    }
    __syncthreads();
    if (tid == 0)
        slots_out[b * BPB + blk] = fmaxf(fmaxf(redbuf[0], redbuf[1]),
                                         fmaxf(redbuf[2], redbuf[3]));
}

__global__ __launch_bounds__(256) void final_kernel(const float* __restrict__ partial,
                                                    const float4* __restrict__ pos4,
                                                    const uint2* __restrict__ aux,
                                                    const float* __restrict__ slots,
                                                    float* __restrict__ out) {
    __shared__ float mxsh;
    const int p = blockIdx.x * 256 + threadIdx.x;  // batch uniform per block
    const int b = p >> 13;
    if (threadIdx.x < 64) {
        float v = slots[b * BPB + (threadIdx.x & 31)];
        #pragma unroll
        for (int o = 16; o > 0; o >>= 1) v = fmaxf(v, __shfl_xor(v, o));
        if (threadIdx.x == 0) mxsh = v;
    }
    __syncthreads();
    float4 f = pos4[p];
    uint2 a = aux[p];
    float md = __uint_as_float(a.x);
    const float* py = partial + ((unsigned long long)(b * M + (int)a.y)) * 3;
    float y0 = py[0], y1 = py[1], y2 = py[2];      // same bits as -0.5*(-2y)
    float inv = 1.0f / (mxsh + 1e-6f);
    float alpha = BASE_ALPHA * (2.0f - md * inv);
    float* po = out + (unsigned long long)p * 3;
    po[0] = fmaf(alpha, y0 - f.x, f.x);
    po[1] = fmaf(alpha, y1 - f.y, f.y);
    po[2] = fmaf(alpha, y2 - f.z, f.z);
}

extern "C" void kernel_launch(void* const* d_in, const int* in_sizes, int n_in,
                              void* d_out, int out_size, void* d_ws, size_t ws_size,
                              hipStream_t stream) {
    const float* pred = (const float*)d_in[0];
    const float* partial = (const float*)d_in[1];
    char* ws = (char*)d_ws;
    float4* pos4 = (float4*)ws;
    uint2* aux = (uint2*)(ws + OFF_AUX);
    float* slot0 = (float*)(ws + OFF_SLOT0);
    float* slot1 = (float*)(ws + OFF_SLOT1);
    unsigned int* maskb = (unsigned int*)(ws + OFF_MASK);
    float* out = (float*)d_out;

    hipLaunchKernelGGL(iter_kernel, dim3(NBLK), dim3(NTHR), 0, stream,
                       pred, partial, pos4, aux, slot0, maskb);
    hipLaunchKernelGGL(light_kernel, dim3(NBLK), dim3(NTHR), 0, stream,
                       partial, pos4, aux, maskb, slot0, slot1);
    hipLaunchKernelGGL(light_kernel, dim3(NBLK), dim3(NTHR), 0, stream,
                       partial, pos4, aux, maskb, slot1, slot0);
    hipLaunchKernelGGL(light_kernel, dim3(NBLK), dim3(NTHR), 0, stream,
                       partial, pos4, aux, maskb, slot0, slot1);
    hipLaunchKernelGGL(final_kernel, dim3(B * N / 256), dim3(256), 0, stream,
                       partial, pos4, aux, slot1, out);
}